// Round 2
// baseline (334.409 us; speedup 1.0000x reference)
//
#include <hip/hip_runtime.h>
#include <stdint.h>

// Problem constants: B=4096, D=256, N=8192, P=4096
// sigma = sqrt(1/(0.07*ln2)); vectors normalized * sigma so MFMA dot is the
// exp2 argument directly: exp(sim/T) = exp2(dot). sigma^2 = 20.6099253
#define K_SIGMA 4.5398156f
#define LN2F    0.6931471805599453f

typedef __attribute__((ext_vector_type(8)))  short short8;
typedef __attribute__((ext_vector_type(16))) float f32x16;

__device__ __forceinline__ float bf2f(uint16_t u) {
  union { uint32_t i; float f; } v; v.i = ((uint32_t)u) << 16; return v.f;
}
__device__ __forceinline__ uint16_t f2bf(float f) {
  union { float f; uint32_t i; } v; v.f = f;
  uint32_t b = v.i;
  b += 0x7FFF + ((b >> 16) & 1);   // RNE
  return (uint16_t)(b >> 16);
}

// ---------------------------------------------------------------------------
// 1) Normalize rows -> bf16*sigma; also zero the rowsum accumulators
//    (replaces the memset dispatch). One wave per row.
// ---------------------------------------------------------------------------
__global__ __launch_bounds__(256) void normalize_kernel(
    const float* __restrict__ z1, const float* __restrict__ z2,
    const float* __restrict__ emb,
    uint16_t* __restrict__ zb, uint16_t* __restrict__ eb,
    float* __restrict__ rs0)
{
  const int gtid = blockIdx.x * 256 + threadIdx.x;
  if (gtid < 12288) rs0[gtid] = 0.0f;    // rs_z[8192] + rs_s[4096]

  const int w = threadIdx.x >> 6, lane = threadIdx.x & 63;
  const int row = blockIdx.x * 4 + w;  // 0..16383
  const float* src;
  uint16_t* dst;
  if (row < 4096)      { src = z1  + row * 256;          dst = zb + row * 256; }
  else if (row < 8192) { src = z2  + (row - 4096) * 256; dst = zb + row * 256; }
  else                 { src = emb + (row - 8192) * 256; dst = eb + (row - 8192) * 256; }
  float4 v = *reinterpret_cast<const float4*>(src + lane * 4);
  float ss = v.x * v.x + v.y * v.y + v.z * v.z + v.w * v.w;
#pragma unroll
  for (int m = 1; m < 64; m <<= 1) ss += __shfl_xor(ss, m);
  float inv = K_SIGMA / fmaxf(sqrtf(ss), 1e-12f);
  ushort4 o;
  o.x = f2bf(v.x * inv); o.y = f2bf(v.y * inv);
  o.z = f2bf(v.z * inv); o.w = f2bf(v.w * inv);
  *reinterpret_cast<ushort4*>(dst + lane * 4) = o;
}

// ---------------------------------------------------------------------------
// 2) Fused sweep, v2: BM=256 (wave owns 64 rows = 2x 32-row tiles),
//    mfma_32x32x16, BN=64 col tile, double-buffered LDS with
//    prefetch-before-compute (2-phase), K=256 held in A-registers.
//    bid < 1024: simclr (32 rb x 32 cc); else spatial (16 rb x 32 cc).
//    Each block sweeps 256 cols = 4 steps of 64.
// ---------------------------------------------------------------------------
__global__ __launch_bounds__(256, 2) void sweep_kernel(
    const uint16_t* __restrict__ zb, const uint16_t* __restrict__ eb,
    const int* __restrict__ anchor,
    float* __restrict__ rs_z, float* __restrict__ rs_s)
{
  __shared__ __align__(16) uint16_t lds[2][64 * 256];   // 2 x 32 KiB
  const int bid  = blockIdx.x;
  const int tid  = threadIdx.x;
  const int w    = tid >> 6;
  const int lane = tid & 63;

  const bool spatial = (bid >= 1024);
  const int sub = spatial ? (bid - 1024) : bid;
  const int rb  = sub >> 5;
  const int cc  = sub & 31;
  const uint16_t* __restrict__ Amat = spatial ? eb : zb;
  const uint16_t* __restrict__ Bmat = spatial ? eb : zb;
  float* __restrict__ rs = spatial ? rs_s : rs_z;

  const int row_base = rb * 256 + w * 64;
  const int hi = lane >> 5;          // half-wave index
  const int ln = lane & 31;

  // A fragments (32x32x16): row = lane&31, k = hi*8 + j; 2 tiles x 16 ksteps
  short8 afrag[2][16];
#pragma unroll
  for (int t = 0; t < 2; ++t) {
    int r  = row_base + t * 32 + ln;
    int sr = spatial ? anchor[r] : r;
    const uint16_t* ap = Amat + sr * 256 + hi * 8;
#pragma unroll
    for (int ks = 0; ks < 16; ++ks)
      afrag[t][ks] = *reinterpret_cast<const short8*>(ap + ks * 16);
  }

  float rsacc[2][16];
#pragma unroll
  for (int t = 0; t < 2; ++t)
#pragma unroll
    for (int r = 0; r < 16; ++r) rsacc[t][r] = 0.0f;

  const int cbase = cc * 256;
  const int r_ = tid >> 5;        // staging row within 8-row group
  const int c_ = tid & 31;        // 16B chunk within row
  const int src_chunk = c_ ^ r_;  // inverse-swizzle on the GLOBAL side

  // stage one 64-col tile into lds[buf]
  auto STAGE = [&](int buf, int step) {
    const int col0 = cbase + step * 64;
#pragma unroll
    for (int it = 0; it < 8; ++it) {
      const uint16_t* src = Bmat + (col0 + it * 8 + r_) * 256 + src_chunk * 8;
      uint16_t* dst = &lds[buf][(it * 8 + r_) * 256 + c_ * 8];  // linear in tid
      __builtin_amdgcn_global_load_lds(
          (const __attribute__((address_space(1))) void*)src,
          (__attribute__((address_space(3))) void*)dst, 16, 0, 0);
    }
  };

  STAGE(0, 0);
  __syncthreads();                 // drains vmcnt(0): tile 0 ready
  int cur = 0;

  for (int step = 0; step < 4; ++step) {
    if (step < 3) STAGE(cur ^ 1, step + 1);   // prefetch overlaps compute

    f32x16 acc[2][2];
#pragma unroll
    for (int t = 0; t < 2; ++t)
#pragma unroll
      for (int ct = 0; ct < 2; ++ct)
#pragma unroll
        for (int r = 0; r < 16; ++r) acc[t][ct][r] = 0.0f;

#pragma unroll
    for (int ks = 0; ks < 16; ++ks) {
#pragma unroll
      for (int ct = 0; ct < 2; ++ct) {
        const int brow = ct * 32 + ln;
        const int ch   = (ks * 2 + hi) ^ (brow & 7);   // swizzled 16B chunk
        short8 bfrag = *reinterpret_cast<const short8*>(&lds[cur][brow * 256 + ch * 8]);
        acc[0][ct] = __builtin_amdgcn_mfma_f32_32x32x16_bf16(afrag[0][ks], bfrag, acc[0][ct], 0, 0, 0);
        acc[1][ct] = __builtin_amdgcn_mfma_f32_32x32x16_bf16(afrag[1][ks], bfrag, acc[1][ct], 0, 0, 0);
      }
    }

    // epilogue: exp2 + per-lane partial rowsums
#pragma unroll
    for (int t = 0; t < 2; ++t)
#pragma unroll
      for (int r = 0; r < 16; ++r)
        rsacc[t][r] += exp2f(acc[t][0][r]) + exp2f(acc[t][1][r]);

    __syncthreads();               // ds_reads done + prefetch landed
    cur ^= 1;
  }

  // C/D layout (32x32): col = lane&31, row = (reg&3) + 8*(reg>>2) + 4*hi.
  // Reduce across the 32 column-lanes within each half-wave, then atomicAdd.
#pragma unroll
  for (int t = 0; t < 2; ++t)
#pragma unroll
    for (int r = 0; r < 16; ++r) {
      float v = rsacc[t][r];
      v += __shfl_xor(v, 1);
      v += __shfl_xor(v, 2);
      v += __shfl_xor(v, 4);
      v += __shfl_xor(v, 8);
      v += __shfl_xor(v, 16);
      if (ln == 0) {
        int row = row_base + t * 32 + (r & 3) + 8 * (r >> 2) + 4 * hi;
        atomicAdd(&rs[row], v);
      }
    }
}

// ---------------------------------------------------------------------------
// 3) Finalize: recompute self/pair dots from the SAME bf16 data (so the
//    huge exp2(self) term cancels against the one inside rowsum), emit loss.
// ---------------------------------------------------------------------------
__global__ __launch_bounds__(256) void finalize_kernel(
    const uint16_t* __restrict__ zb, const uint16_t* __restrict__ eb,
    const int* __restrict__ anchor, const int* __restrict__ neighbor,
    const float* __restrict__ rs_z, const float* __restrict__ rs_s,
    float* __restrict__ loss_z, float* __restrict__ loss_s)
{
  const int w = threadIdx.x >> 6, lane = threadIdx.x & 63;
  const int row = blockIdx.x * 4 + w;   // 0..12287
  const uint16_t *pa, *pb;
  const bool is_z = (row < 8192);
  int idx;
  bool same = false;
  if (is_z) {
    idx = row;
    int pair = (row < 4096) ? row + 4096 : row - 4096;
    pa = zb + row * 256;
    pb = zb + pair * 256;
  } else {
    idx = row - 8192;
    int ai = anchor[idx], ni = neighbor[idx];
    same = (ai == ni);
    pa = eb + ai * 256;
    pb = eb + ni * 256;
  }
  ushort4 ua = *reinterpret_cast<const ushort4*>(pa + lane * 4);
  ushort4 ub = *reinterpret_cast<const ushort4*>(pb + lane * 4);
  float a0 = bf2f(ua.x), a1 = bf2f(ua.y), a2 = bf2f(ua.z), a3 = bf2f(ua.w);
  float b0 = bf2f(ub.x), b1 = bf2f(ub.y), b2 = bf2f(ub.z), b3 = bf2f(ub.w);
  float dd = a0 * a0 + a1 * a1 + a2 * a2 + a3 * a3;  // self-dot (scaled)
  float dn = a0 * b0 + a1 * b1 + a2 * b2 + a3 * b3;  // pair/neighbor dot
#pragma unroll
  for (int m = 1; m < 64; m <<= 1) {
    dd += __shfl_xor(dd, m);
    dn += __shfl_xor(dn, m);
  }
  if (lane == 0) {
    if (is_z) {
      loss_z[idx] = logf(rs_z[idx] - exp2f(dd)) - dn * LN2F;
    } else {
      float S = rs_s[idx] - exp2f(dd) + (same ? exp2f(dn) : 0.0f);
      loss_s[idx] = logf(S) - dn * LN2F;
    }
  }
}

// ---------------------------------------------------------------------------
// 4) Reduce per-row losses -> out[0] (simclr mean), out[1] (spatial mean)
// ---------------------------------------------------------------------------
__global__ __launch_bounds__(256) void reduce_kernel(
    const float* __restrict__ loss_z, const float* __restrict__ loss_s,
    float* __restrict__ out)
{
  const int which = blockIdx.x;
  const float* src = which ? loss_s : loss_z;
  const int n = which ? 4096 : 8192;
  float s = 0.0f;
  for (int i = threadIdx.x; i < n; i += 256) s += src[i];
#pragma unroll
  for (int m = 1; m < 64; m <<= 1) s += __shfl_xor(s, m);
  __shared__ float ps[4];
  if ((threadIdx.x & 63) == 0) ps[threadIdx.x >> 6] = s;
  __syncthreads();
  if (threadIdx.x == 0)
    out[which] = (ps[0] + ps[1] + ps[2] + ps[3]) * (which ? (1.0f / 4096.0f) : (1.0f / 8192.0f));
}

// ---------------------------------------------------------------------------
extern "C" void kernel_launch(void* const* d_in, const int* in_sizes, int n_in,
                              void* d_out, int out_size, void* d_ws, size_t ws_size,
                              hipStream_t stream) {
  const float* z1      = (const float*)d_in[0];
  const float* z2      = (const float*)d_in[1];
  const float* emb     = (const float*)d_in[2];
  const int*   anchor  = (const int*)d_in[3];
  const int*   neighbor= (const int*)d_in[4];
  float* out = (float*)d_out;

  float* ws      = (float*)d_ws;
  float* rs_z    = ws;              // 8192 f32
  float* rs_s    = ws + 8192;       // 4096 f32
  float* loss_z  = ws + 12288;      // 8192 f32
  float* loss_s  = ws + 20480;      // 4096 f32
  uint16_t* zb   = (uint16_t*)(ws + 24576);   // 8192*256 bf16 (4 MiB)
  uint16_t* eb   = zb + 8192 * 256;           // 8192*256 bf16 (4 MiB)

  normalize_kernel<<<4096, 256, 0, stream>>>(z1, z2, emb, zb, eb, ws);
  sweep_kernel<<<1536, 256, 0, stream>>>(zb, eb, anchor, rs_z, rs_s);
  finalize_kernel<<<3072, 256, 0, stream>>>(zb, eb, anchor, neighbor,
                                            rs_z, rs_s, loss_z, loss_s);
  reduce_kernel<<<2, 256, 0, stream>>>(loss_z, loss_s, out);
}